// Round 9
// baseline (413.982 us; speedup 1.0000x reference)
//
#include <hip/hip_runtime.h>
#include <hip/hip_bf16.h>

#define SEQ   2048
#define BATCH 2
#define NH    16
#define HD    64
#define DM    1024

typedef unsigned short u16;
typedef unsigned int   u32;
typedef __attribute__((ext_vector_type(8))) short bf8;   // 8 bf16 in 4 VGPRs
typedef __attribute__((ext_vector_type(4))) float f4;

__device__ inline u16 f2bf(float f) {                    // round-to-nearest-even
    u32 u = __builtin_bit_cast(u32, f);
    return (u16)((u + 0x7FFFu + ((u >> 16) & 1u)) >> 16);
}

__device__ inline f4 MFMA(bf8 a, bf8 b, f4 c) {
    return __builtin_amdgcn_mfma_f32_16x16x32_bf16(a, b, c, 0, 0, 0);
}

// async global->LDS, 16B per lane (m97 lever)
__device__ inline void gload16(const u16* g, u16* l) {
    __builtin_amdgcn_global_load_lds(
        (const __attribute__((address_space(1))) unsigned int*)(const void*)g,
        (__attribute__((address_space(3))) unsigned int*)(void*)l, 16, 0, 0);
}

// ---------------------------------------------------------------------------
// fused fp32 -> bf16 cast for x, W_qkv, W_out
// ---------------------------------------------------------------------------
#define N4_X  1048576
#define N4_WQ 786432
#define N4_WO 262144
__global__ __launch_bounds__(256) void cast_all(const float* __restrict__ x,
                                                const float* __restrict__ wq,
                                                const float* __restrict__ wo,
                                                u16* __restrict__ xb,
                                                u16* __restrict__ wqb,
                                                u16* __restrict__ wob) {
    const int i = blockIdx.x * 256 + threadIdx.x;
    const float* src;
    u16* dst;
    int j;
    if (i < N4_X)                { src = x;  dst = xb;  j = i; }
    else if (i < N4_X + N4_WQ)   { src = wq; dst = wqb; j = i - N4_X; }
    else                         { src = wo; dst = wob; j = i - N4_X - N4_WQ; }
    const float4 v = ((const float4*)src)[j];
    ushort4 o;
    o.x = f2bf(v.x); o.y = f2bf(v.y); o.z = f2bf(v.z); o.w = f2bf(v.w);
    ((ushort4*)dst)[j] = o;
}

// ---------------------------------------------------------------------------
// bf16 MFMA GEMM (m97 structure): 128x128 tile, 4 waves, 4x4 frags 16x16x32,
// BK=32, unpadded [128][32] LDS via global_load_lds dwordx4.
// MODE 0: qkv epilogue (scatter bf16 into q/k/v [B,H,S,hd]); MODE 1: fp32 out.
// ---------------------------------------------------------------------------
template<int MODE>
__global__ __launch_bounds__(256) void gemm_bf16(const u16* __restrict__ A,
                                                 const u16* __restrict__ Bm,
                                                 const float* __restrict__ bias,
                                                 u16* __restrict__ q_o,
                                                 u16* __restrict__ k_o,
                                                 u16* __restrict__ v_o,
                                                 float* __restrict__ f_o) {
    __shared__ __align__(16) u16 Al[128 * 32];
    __shared__ __align__(16) u16 Bl[128 * 32];
    const int t  = threadIdx.x;
    const int l  = t & 63, w = t >> 6;
    const int n0 = blockIdx.x * 128, m0 = blockIdx.y * 128;
    const int wr = w >> 1, wc = w & 1;
    const int lr16 = l & 15, lg = l >> 4;

    const f4 zf = {0.f, 0.f, 0.f, 0.f};
    f4 acc[4][4];
#pragma unroll
    for (int m = 0; m < 4; ++m)
#pragma unroll
        for (int n = 0; n < 4; ++n) acc[m][n] = zf;

    const int rw = t >> 2;
    const int kc = t & 3;

    for (int k0 = 0; k0 < DM; k0 += 32) {
        __syncthreads();
        gload16(&A[(size_t)(m0 + rw) * DM + k0 + kc * 8],       &Al[rw * 32 + kc * 8]);
        gload16(&A[(size_t)(m0 + 64 + rw) * DM + k0 + kc * 8],  &Al[(64 + rw) * 32 + kc * 8]);
        gload16(&Bm[(size_t)(n0 + rw) * DM + k0 + kc * 8],      &Bl[rw * 32 + kc * 8]);
        gload16(&Bm[(size_t)(n0 + 64 + rw) * DM + k0 + kc * 8], &Bl[(64 + rw) * 32 + kc * 8]);
        __syncthreads();
        bf8 af[4], bfr[4];
#pragma unroll
        for (int m = 0; m < 4; ++m)
            af[m] = *(const bf8*)&Al[(wr * 64 + m * 16 + lr16) * 32 + lg * 8];
#pragma unroll
        for (int n = 0; n < 4; ++n)
            bfr[n] = *(const bf8*)&Bl[(wc * 64 + n * 16 + lr16) * 32 + lg * 8];
        __builtin_amdgcn_s_setprio(1);
#pragma unroll
        for (int m = 0; m < 4; ++m)
#pragma unroll
            for (int n = 0; n < 4; ++n)
                acc[m][n] = MFMA(af[m], bfr[n], acc[m][n]);
        __builtin_amdgcn_s_setprio(0);
    }

#pragma unroll
    for (int m = 0; m < 4; ++m)
#pragma unroll
        for (int n = 0; n < 4; ++n)
#pragma unroll
            for (int r = 0; r < 4; ++r) {
                const int M = m0 + wr * 64 + m * 16 + lg * 4 + r;
                const int N = n0 + wc * 64 + n * 16 + lr16;
                const float val = acc[m][n][r] + bias[N];
                if (MODE == 0) {
                    const int b = M >> 11, s = M & (SEQ - 1);
                    const int h = N / 192, f = N % 192;
                    const int seg = f >> 6, c = f & 63;
                    u16* dst = (seg == 0) ? q_o : ((seg == 1) ? k_o : v_o);
                    dst[(((size_t)(b * NH + h)) * SEQ + s) * HD + c] = f2bf(val);
                } else {
                    f_o[(size_t)M * DM + N] = val;
                }
            }
}

// ---------------------------------------------------------------------------
// V transpose: v [BH][S][64] -> vt [BH][64][S]
// ---------------------------------------------------------------------------
__global__ __launch_bounds__(256) void v_transpose(const u16* __restrict__ v,
                                                   u16* __restrict__ vt) {
    __shared__ u16 tl[64][65];
    const int t  = threadIdx.x;
    const int s0 = blockIdx.x * 64;
    const int bh = blockIdx.y;
    const u16* src = v + ((size_t)bh * SEQ + s0) * HD;
#pragma unroll
    for (int i = 0; i < 2; ++i) {
        const int c = i * 256 + t, s = c >> 3, cc = c & 7;
        const float4 d = *(const float4*)&src[s * HD + cc * 8];
        const u16* dp = (const u16*)&d;
#pragma unroll
        for (int j = 0; j < 8; ++j) tl[s][cc * 8 + j] = dp[j];
    }
    __syncthreads();
    u16* dst = vt + (size_t)bh * HD * SEQ + s0;
#pragma unroll
    for (int i = 0; i < 2; ++i) {
        const int c = i * 256 + t, dim = c >> 3, sc = c & 7;
        __align__(16) u16 tmp[8];
#pragma unroll
        for (int j = 0; j < 8; ++j) tmp[j] = tl[sc * 8 + j][dim];
        *(float4*)&dst[(size_t)dim * SEQ + sc * 8] = *(const float4*)tmp;
    }
}

// ---------------------------------------------------------------------------
// MFMA flash attention v4: ONE WAVE PER BLOCK, zero barriers.
// 16 q-rows per wave; K/V fragments loaded global->reg (K/V is L2/L3-resident,
// LDS staging of cached data is pure overhead). LDS only for the wave-private
// 2.3KB P roundtrip + staged epilogue. log2-domain softmax, lane-partial l,
// deferred-max (THR=8). Grid 4096x64: ~12 independent chains/CU cover each
// other's latencies; block id = qt*32+bh pins bh%8 to one XCD's L2.
// ---------------------------------------------------------------------------
#define KS 72
__global__ __launch_bounds__(64, 3) void flash_attn(const u16* __restrict__ qg,
                                                    const u16* __restrict__ kg,
                                                    const u16* __restrict__ vtg,
                                                    const float* __restrict__ mask,
                                                    u16* __restrict__ og) {
    __shared__ __align__(16) u16 Pw[16 * KS];
    const int l = threadIdx.x;
    const int lr16 = l & 15, lg = l >> 4;
    const int bx = blockIdx.x;
    const int qt = bx >> 5, bh = bx & 31;
    const int h = bh & 15, b = bh >> 4;
    const int qbase = qt * 16;

    const float C1  = 0.18033688011f;   // 0.125 * log2(e)
    const float L2E = 1.44269504089f;

    bf8 qf[2];
    {
        const u16* qp = qg + ((size_t)bh * SEQ + qbase + lr16) * HD + lg * 8;
        qf[0] = *(const bf8*)qp;
        qf[1] = *(const bf8*)(qp + 32);
    }

    const f4 zf = {0.f, 0.f, 0.f, 0.f};
    f4 Oa[4];
    float mr[4], lp[4];
#pragma unroll
    for (int n = 0; n < 4; ++n) Oa[n] = zf;
#pragma unroll
    for (int r = 0; r < 4; ++r) { mr[r] = -1e30f; lp[r] = 0.f; }

    const u16* Kb  = kg  + (size_t)bh * SEQ * HD;
    const u16* Vtb = vtg + (size_t)bh * HD * SEQ;
    const float* Mrow = mask + (size_t)(qbase + lg * 4) * SEQ;   // + r*SEQ

    for (int kt = 0; kt < 32; ++kt) {
        const int kv0 = kt * 64;
        // ---- issue all loads up front; vmcnt ordering pipelines them
        float mk[4][4];
#pragma unroll
        for (int n = 0; n < 4; ++n)
#pragma unroll
            for (int r = 0; r < 4; ++r)
                mk[n][r] = Mrow[(size_t)r * SEQ + kv0 + n * 16 + lr16] * L2E;
        bf8 kf[4][2], vf[4][2];
#pragma unroll
        for (int n = 0; n < 4; ++n) {
            const u16* kp = &Kb[(size_t)(kv0 + n * 16 + lr16) * HD + lg * 8];
            kf[n][0] = *(const bf8*)kp;
            kf[n][1] = *(const bf8*)(kp + 32);
            const u16* vp = &Vtb[(size_t)(n * 16 + lr16) * SEQ + kv0 + lg * 8];
            vf[n][0] = *(const bf8*)vp;
            vf[n][1] = *(const bf8*)(vp + 32);
        }
        // ---- QK^T
        f4 sc[4];
        __builtin_amdgcn_s_setprio(1);
#pragma unroll
        for (int n = 0; n < 4; ++n)
            sc[n] = MFMA(qf[1], kf[n][1], MFMA(qf[0], kf[n][0], zf));
        __builtin_amdgcn_s_setprio(0);
#pragma unroll
        for (int n = 0; n < 4; ++n)
#pragma unroll
            for (int r = 0; r < 4; ++r)
                sc[n][r] = fmaf(sc[n][r], C1, mk[n][r]);
        // ---- lane-local max trigger; full reduce+rescale only when needed
        float lmax[4];
        bool need = false;
#pragma unroll
        for (int r = 0; r < 4; ++r) {
            lmax[r] = fmaxf(fmaxf(sc[0][r], sc[1][r]), fmaxf(sc[2][r], sc[3][r]));
            need |= (lmax[r] > mr[r] + 8.f);
        }
        if (__any(need)) {
#pragma unroll
            for (int r = 0; r < 4; ++r) {
                float mx = lmax[r];
#pragma unroll
                for (int d = 1; d < 16; d <<= 1) mx = fmaxf(mx, __shfl_xor(mx, d));
                const float mn = fmaxf(mr[r], mx);
                const float al = exp2f(mr[r] - mn);
                mr[r] = mn;
                lp[r] *= al;
#pragma unroll
                for (int n = 0; n < 4; ++n) Oa[n][r] *= al;
            }
        }
        // ---- P = 2^(s-mr) (<=2^8), lane-partial l, wave-private LDS roundtrip
#pragma unroll
        for (int r = 0; r < 4; ++r) {
            float ps = 0.f;
#pragma unroll
            for (int n = 0; n < 4; ++n) {
                const float p = exp2f(sc[n][r] - mr[r]);
                ps += p;
                const __hip_bfloat16 hb = __float2bfloat16(p);
                Pw[(lg * 4 + r) * KS + n * 16 + lr16] = __builtin_bit_cast(u16, hb);
            }
            lp[r] += ps;
        }
        asm volatile("s_waitcnt lgkmcnt(0)" ::: "memory");
        const bf8 pf0 = *(const bf8*)&Pw[lr16 * KS + lg * 8];
        const bf8 pf1 = *(const bf8*)&Pw[lr16 * KS + 32 + lg * 8];
        // ---- PV
        __builtin_amdgcn_s_setprio(1);
#pragma unroll
        for (int n = 0; n < 4; ++n) {
            Oa[n] = MFMA(pf0, vf[n][0], Oa[n]);
            Oa[n] = MFMA(pf1, vf[n][1], Oa[n]);
        }
        __builtin_amdgcn_s_setprio(0);
    }

    // ---- epilogue: final l reduce, normalize, LDS stage, 16B stores
    float inv[4];
#pragma unroll
    for (int r = 0; r < 4; ++r) {
        float s = lp[r];
#pragma unroll
        for (int d = 1; d < 16; d <<= 1) s += __shfl_xor(s, d);
        inv[r] = 1.f / s;
    }
    u16* Ol = Pw;
#pragma unroll
    for (int n = 0; n < 4; ++n)
#pragma unroll
        for (int r = 0; r < 4; ++r)
            Ol[(lg * 4 + r) * KS + n * 16 + lr16] = f2bf(Oa[n][r] * inv[r]);
    asm volatile("s_waitcnt lgkmcnt(0)" ::: "memory");
    {
        const int row = l >> 2, c0 = (l & 3) * 16;
        const u16* src = &Ol[row * KS + c0];
        u16* dstp = og + ((size_t)(b * SEQ + qbase + row)) * DM + h * HD + c0;
        *(float4*)dstp       = *(const float4*)src;
        *(float4*)(dstp + 8) = *(const float4*)(src + 8);
    }
}

// ---------------------------------------------------------------------------
extern "C" void kernel_launch(void* const* d_in, const int* in_sizes, int n_in,
                              void* d_out, int out_size, void* d_ws, size_t ws_size,
                              hipStream_t stream) {
    const float* x     = (const float*)d_in[0];
    const float* mask  = (const float*)d_in[1];
    const float* W_qkv = (const float*)d_in[2];
    const float* b_qkv = (const float*)d_in[3];
    const float* W_out = (const float*)d_in[4];
    const float* b_out = (const float*)d_in[5];
    float* out = (float*)d_out;

    const size_t NQ = (size_t)BATCH * NH * SEQ * HD;      // 4M elems
    u16* ws  = (u16*)d_ws;
    u16* xb  = ws;
    u16* wqb = xb + (size_t)4096 * 1024;
    u16* wob = wqb + (size_t)3072 * 1024;
    u16* qb  = wob + (size_t)1024 * 1024;
    u16* kb  = qb + NQ;
    u16* vb  = kb + NQ;
    u16* vtb = vb + NQ;
    u16* ob  = vtb + NQ;

    cast_all<<<(N4_X + N4_WQ + N4_WO) / 256, 256, 0, stream>>>(x, W_qkv, W_out, xb, wqb, wob);
    gemm_bf16<0><<<dim3(24, 32), 256, 0, stream>>>(xb, wqb, b_qkv, qb, kb, vb, nullptr);
    v_transpose<<<dim3(32, 32), 256, 0, stream>>>(vb, vtb);
    flash_attn<<<dim3((SEQ / 16) * NH * BATCH), 64, 0, stream>>>(qb, kb, vtb, mask, ob);
    gemm_bf16<1><<<dim3(8, 32), 256, 0, stream>>>(ob, wob, b_out, nullptr, nullptr, nullptr, out);
}

// Round 10
// 410.276 us; speedup vs baseline: 1.0090x; 1.0090x over previous
//
#include <hip/hip_runtime.h>
#include <hip/hip_bf16.h>

#define SEQ   2048
#define BATCH 2
#define NH    16
#define HD    64
#define DM    1024

typedef unsigned short u16;
typedef unsigned int   u32;
typedef __attribute__((ext_vector_type(8))) short bf8;   // 8 bf16 in 4 VGPRs
typedef __attribute__((ext_vector_type(4))) float f4;
typedef __attribute__((ext_vector_type(4))) u32  u32x4;

__device__ inline u16 f2bf(float f) {                    // round-to-nearest-even
    u32 u = __builtin_bit_cast(u32, f);
    return (u16)((u + 0x7FFFu + ((u >> 16) & 1u)) >> 16);
}

__device__ inline f4 MFMA(bf8 a, bf8 b, f4 c) {
    return __builtin_amdgcn_mfma_f32_16x16x32_bf16(a, b, c, 0, 0, 0);
}

// async global->LDS, 16B per lane (m97 lever)
__device__ inline void gload16(const u16* g, u16* l) {
    __builtin_amdgcn_global_load_lds(
        (const __attribute__((address_space(1))) unsigned int*)(const void*)g,
        (__attribute__((address_space(3))) unsigned int*)(void*)l, 16, 0, 0);
}

// ---------------------------------------------------------------------------
// fused fp32 -> bf16 cast for x, W_qkv, W_out
// ---------------------------------------------------------------------------
#define N4_X  1048576
#define N4_WQ 786432
#define N4_WO 262144
__global__ __launch_bounds__(256) void cast_all(const float* __restrict__ x,
                                                const float* __restrict__ wq,
                                                const float* __restrict__ wo,
                                                u16* __restrict__ xb,
                                                u16* __restrict__ wqb,
                                                u16* __restrict__ wob) {
    const int i = blockIdx.x * 256 + threadIdx.x;
    const float* src;
    u16* dst;
    int j;
    if (i < N4_X)                { src = x;  dst = xb;  j = i; }
    else if (i < N4_X + N4_WQ)   { src = wq; dst = wqb; j = i - N4_X; }
    else                         { src = wo; dst = wob; j = i - N4_X - N4_WQ; }
    const float4 v = ((const float4*)src)[j];
    ushort4 o;
    o.x = f2bf(v.x); o.y = f2bf(v.y); o.z = f2bf(v.z); o.w = f2bf(v.w);
    ((ushort4*)dst)[j] = o;
}

// ---------------------------------------------------------------------------
// bf16 MFMA GEMM (m97 structure): 128x128 tile, 4 waves, 4x4 frags 16x16x32,
// BK=32, unpadded [128][32] LDS via global_load_lds dwordx4.
// MODE 0: qkv epilogue (scatter bf16 into q/k/v [B,H,S,hd]); MODE 1: fp32 out.
// ---------------------------------------------------------------------------
template<int MODE>
__global__ __launch_bounds__(256) void gemm_bf16(const u16* __restrict__ A,
                                                 const u16* __restrict__ Bm,
                                                 const float* __restrict__ bias,
                                                 u16* __restrict__ q_o,
                                                 u16* __restrict__ k_o,
                                                 u16* __restrict__ v_o,
                                                 float* __restrict__ f_o) {
    __shared__ __align__(16) u16 Al[128 * 32];
    __shared__ __align__(16) u16 Bl[128 * 32];
    const int t  = threadIdx.x;
    const int l  = t & 63, w = t >> 6;
    const int n0 = blockIdx.x * 128, m0 = blockIdx.y * 128;
    const int wr = w >> 1, wc = w & 1;
    const int lr16 = l & 15, lg = l >> 4;

    const f4 zf = {0.f, 0.f, 0.f, 0.f};
    f4 acc[4][4];
#pragma unroll
    for (int m = 0; m < 4; ++m)
#pragma unroll
        for (int n = 0; n < 4; ++n) acc[m][n] = zf;

    const int rw = t >> 2;
    const int kc = t & 3;

    for (int k0 = 0; k0 < DM; k0 += 32) {
        __syncthreads();
        gload16(&A[(size_t)(m0 + rw) * DM + k0 + kc * 8],       &Al[rw * 32 + kc * 8]);
        gload16(&A[(size_t)(m0 + 64 + rw) * DM + k0 + kc * 8],  &Al[(64 + rw) * 32 + kc * 8]);
        gload16(&Bm[(size_t)(n0 + rw) * DM + k0 + kc * 8],      &Bl[rw * 32 + kc * 8]);
        gload16(&Bm[(size_t)(n0 + 64 + rw) * DM + k0 + kc * 8], &Bl[(64 + rw) * 32 + kc * 8]);
        __syncthreads();
        bf8 af[4], bfr[4];
#pragma unroll
        for (int m = 0; m < 4; ++m)
            af[m] = *(const bf8*)&Al[(wr * 64 + m * 16 + lr16) * 32 + lg * 8];
#pragma unroll
        for (int n = 0; n < 4; ++n)
            bfr[n] = *(const bf8*)&Bl[(wc * 64 + n * 16 + lr16) * 32 + lg * 8];
        __builtin_amdgcn_s_setprio(1);
#pragma unroll
        for (int m = 0; m < 4; ++m)
#pragma unroll
            for (int n = 0; n < 4; ++n)
                acc[m][n] = MFMA(af[m], bfr[n], acc[m][n]);
        __builtin_amdgcn_s_setprio(0);
    }

#pragma unroll
    for (int m = 0; m < 4; ++m)
#pragma unroll
        for (int n = 0; n < 4; ++n)
#pragma unroll
            for (int r = 0; r < 4; ++r) {
                const int M = m0 + wr * 64 + m * 16 + lg * 4 + r;
                const int N = n0 + wc * 64 + n * 16 + lr16;
                const float val = acc[m][n][r] + bias[N];
                if (MODE == 0) {
                    const int b = M >> 11, s = M & (SEQ - 1);
                    const int h = N / 192, f = N % 192;
                    const int seg = f >> 6, c = f & 63;
                    u16* dst = (seg == 0) ? q_o : ((seg == 1) ? k_o : v_o);
                    dst[(((size_t)(b * NH + h)) * SEQ + s) * HD + c] = f2bf(val);
                } else {
                    f_o[(size_t)M * DM + N] = val;
                }
            }
}

// ---------------------------------------------------------------------------
// V transpose: v [BH][S][64] -> vt [BH][64][S]
// ---------------------------------------------------------------------------
__global__ __launch_bounds__(256) void v_transpose(const u16* __restrict__ v,
                                                   u16* __restrict__ vt) {
    __shared__ u16 tl[64][65];
    const int t  = threadIdx.x;
    const int s0 = blockIdx.x * 64;
    const int bh = blockIdx.y;
    const u16* src = v + ((size_t)bh * SEQ + s0) * HD;
#pragma unroll
    for (int i = 0; i < 2; ++i) {
        const int c = i * 256 + t, s = c >> 3, cc = c & 7;
        const float4 d = *(const float4*)&src[s * HD + cc * 8];
        const u16* dp = (const u16*)&d;
#pragma unroll
        for (int j = 0; j < 8; ++j) tl[s][cc * 8 + j] = dp[j];
    }
    __syncthreads();
    u16* dst = vt + (size_t)bh * HD * SEQ + s0;
#pragma unroll
    for (int i = 0; i < 2; ++i) {
        const int c = i * 256 + t, dim = c >> 3, sc = c & 7;
        __align__(16) u16 tmp[8];
#pragma unroll
        for (int j = 0; j < 8; ++j) tmp[j] = tl[sc * 8 + j][dim];
        *(float4*)&dst[(size_t)dim * SEQ + sc * 8] = *(const float4*)tmp;
    }
}

// ---------------------------------------------------------------------------
// MFMA flash attention v5: round-6 geometry (4 waves x 16q, shared dbuf K/V,
// 1 barrier/tile) + SWAPPED QK^T (S = mfma(K,Q) -> lane owns one q=lr16):
//  - softmax lane-local (15 fmax + 2 shfl), lane-partial l, deferred max
//  - P -> PV A-frag via 16 bpermute + 8 select in-register (NO P LDS roundtrip)
//  - mask as float4 loads (4/tile, prefetched 1 ahead)
//  - LDS 36KB -> 4 blocks/CU; chunked XCD map (4 full (b,h) per XCD L2)
// ---------------------------------------------------------------------------
#define KS 72
__global__ __launch_bounds__(256, 4) void flash_attn(const u16* __restrict__ qg,
                                                     const u16* __restrict__ kg,
                                                     const u16* __restrict__ vtg,
                                                     const float* __restrict__ mask,
                                                     u16* __restrict__ og) {
    __shared__ __align__(16) u16 Kl[2][64 * KS];
    __shared__ __align__(16) u16 Vl[2][64 * KS];
    const int t = threadIdx.x, l = t & 63, w = t >> 6;
    const int lr16 = l & 15, lg = l >> 4;
    // chunked XCD map: hw bid -> logical; XCD x owns logical [x*128,(x+1)*128)
    // = 4 complete (b,h) K/V sets (2MB) resident in its L2.
    const int bid = blockIdx.x;
    const int lb  = (bid & 7) * 128 + (bid >> 3);
    const int bh  = lb >> 5, qt = lb & 31;
    const int h = bh & 15, b = bh >> 4;
    const int q0 = qt * 64;
    const int qbase = q0 + w * 16;

    const float C1  = 0.18033688011f;   // 0.125 * log2(e)
    const float L2E = 1.44269504089f;

    // Q as B-operand frag: lane holds Q[q=qbase+lr16][d=lg*8+j]
    bf8 qf[2];
    {
        const u16* qp = qg + ((size_t)bh * SEQ + qbase + lr16) * HD + lg * 8;
        qf[0] = *(const bf8*)qp;
        qf[1] = *(const bf8*)(qp + 32);
    }

    const f4 zf = {0.f, 0.f, 0.f, 0.f};
    f4 Oa[4];                       // O[q=lg*4+r][dim=n*16+lr16]
#pragma unroll
    for (int n = 0; n < 4; ++n) Oa[n] = zf;
    float mr = -1e30f, lp = 0.f;    // per-lane softmax state for q = lr16

    const u16* Kb = kg  + (size_t)bh * SEQ * HD;
    const u16* Vb = vtg + (size_t)bh * HD * SEQ;

    float4 kvr[2], vvr[2];
    f4 mk[4], mkn[4];               // mask*log2e, one float4 per kb

    auto issue_kv = [&](int kv0) {
#pragma unroll
        for (int i = 0; i < 2; ++i) {
            const int c = i * 256 + t, a = c >> 3, cc = c & 7;
            kvr[i] = *(const float4*)&Kb[(size_t)(kv0 + a) * HD + cc * 8];
            vvr[i] = *(const float4*)&Vb[(size_t)a * SEQ + kv0 + cc * 8];
        }
    };
    auto write_kv = [&](int buf) {
#pragma unroll
        for (int i = 0; i < 2; ++i) {
            const int c = i * 256 + t, a = c >> 3, cc = c & 7;
            *(float4*)&Kl[buf][a * KS + cc * 8] = kvr[i];
            *(float4*)&Vl[buf][a * KS + cc * 8] = vvr[i];
        }
    };
    auto issue_mask = [&](f4 (&mm)[4], int kv0) {
        const float* mrow = &mask[(size_t)(qbase + lr16) * SEQ + kv0 + lg * 4];
#pragma unroll
        for (int kb = 0; kb < 4; ++kb) {
            f4 v = *(const f4*)(mrow + kb * 16);
#pragma unroll
            for (int r = 0; r < 4; ++r) v[r] *= L2E;
            mm[kb] = v;
        }
    };

    issue_kv(0);
    issue_mask(mk, 0);
    write_kv(0);
    issue_kv(64);
    issue_mask(mkn, 64);
    __syncthreads();

    for (int kt = 0; kt < 32; ++kt) {
        const int cur = kt & 1;
        // ---- swapped QK^T: sc[kb] = S[key=kb*16+lg*4+r][q=lr16]
        f4 sc[4];
        __builtin_amdgcn_s_setprio(1);
#pragma unroll
        for (int kb = 0; kb < 4; ++kb) {
            const bf8 k0 = *(const bf8*)&Kl[cur][(kb * 16 + lr16) * KS + lg * 8];
            const bf8 k1 = *(const bf8*)&Kl[cur][(kb * 16 + lr16) * KS + 32 + lg * 8];
            sc[kb] = MFMA(k1, qf[1], MFMA(k0, qf[0], zf));
        }
        __builtin_amdgcn_s_setprio(0);
#pragma unroll
        for (int kb = 0; kb < 4; ++kb)
#pragma unroll
            for (int r = 0; r < 4; ++r)
                sc[kb][r] = fmaf(sc[kb][r], C1, mk[kb][r]);
        // ---- row max: 15 local fmax + 2 shfl (q's k-range spans lg groups)
        float rmax = fmaxf(
            fmaxf(fmaxf(fmaxf(sc[0][0], sc[0][1]), fmaxf(sc[0][2], sc[0][3])),
                  fmaxf(fmaxf(sc[1][0], sc[1][1]), fmaxf(sc[1][2], sc[1][3]))),
            fmaxf(fmaxf(fmaxf(sc[2][0], sc[2][1]), fmaxf(sc[2][2], sc[2][3])),
                  fmaxf(fmaxf(sc[3][0], sc[3][1]), fmaxf(sc[3][2], sc[3][3]))));
        rmax = fmaxf(rmax, __shfl_xor(rmax, 16));
        rmax = fmaxf(rmax, __shfl_xor(rmax, 32));
        // ---- deferred rescale (rare)
        if (__any(rmax > mr + 8.f)) {
            const float mn = fmaxf(mr, rmax);
            const float al = exp2f(mr - mn);
            mr = mn;
            lp *= al;
            float alr[4];
#pragma unroll
            for (int r = 0; r < 4; ++r) alr[r] = __shfl(al, lg * 4 + r);
#pragma unroll
            for (int n = 0; n < 4; ++n)
#pragma unroll
                for (int r = 0; r < 4; ++r) Oa[n][r] *= alr[r];
        }
        // ---- P = 2^(s-mr) (<=2^8), lane-partial l, pack to bf16 pairs
        u32 pk[4][2];
#pragma unroll
        for (int kb = 0; kb < 4; ++kb) {
            const float p0 = exp2f(sc[kb][0] - mr);
            const float p1 = exp2f(sc[kb][1] - mr);
            const float p2 = exp2f(sc[kb][2] - mr);
            const float p3 = exp2f(sc[kb][3] - mr);
            lp += (p0 + p1) + (p2 + p3);
            pk[kb][0] = ((u32)f2bf(p1) << 16) | f2bf(p0);
            pk[kb][1] = ((u32)f2bf(p3) << 16) | f2bf(p2);
        }
        // ---- redistribute P -> PV A-frag: lane needs P[q=lr16][k=lg*8+j]
        // sources: lanes (lg&1)*32+lr16 and +16; register set kb = (half*2)+(lg>>1)
        const int s0 = (lg & 1) * 32 + lr16, s1 = s0 + 16;
        const bool hi = (lg & 2) != 0;
        u32x4 paw[2];
#pragma unroll
        for (int hf = 0; hf < 2; ++hf) {
            const int kbA = hf * 2, kbB = hf * 2 + 1;
            const u32 a0 = (u32)__shfl((int)pk[kbA][0], s0);
            const u32 a1 = (u32)__shfl((int)pk[kbA][1], s0);
            const u32 a2 = (u32)__shfl((int)pk[kbA][0], s1);
            const u32 a3 = (u32)__shfl((int)pk[kbA][1], s1);
            const u32 b0 = (u32)__shfl((int)pk[kbB][0], s0);
            const u32 b1 = (u32)__shfl((int)pk[kbB][1], s0);
            const u32 b2 = (u32)__shfl((int)pk[kbB][0], s1);
            const u32 b3 = (u32)__shfl((int)pk[kbB][1], s1);
            paw[hf][0] = hi ? b0 : a0;
            paw[hf][1] = hi ? b1 : a1;
            paw[hf][2] = hi ? b2 : a2;
            paw[hf][3] = hi ? b3 : a3;
        }
        const bf8 pa0 = __builtin_bit_cast(bf8, paw[0]);
        const bf8 pa1 = __builtin_bit_cast(bf8, paw[1]);
        // ---- PV: Oa[n] += P[q][k] * V[k][dim=n*16+lr16]
        __builtin_amdgcn_s_setprio(1);
#pragma unroll
        for (int n = 0; n < 4; ++n) {
            const bf8 v0 = *(const bf8*)&Vl[cur][(n * 16 + lr16) * KS + lg * 8];
            const bf8 v1 = *(const bf8*)&Vl[cur][(n * 16 + lr16) * KS + 32 + lg * 8];
            Oa[n] = MFMA(pa1, v1, MFMA(pa0, v0, Oa[n]));
        }
        __builtin_amdgcn_s_setprio(0);
        // ---- stage next tile; prefetch tile after
        if (kt < 31) {
            write_kv(cur ^ 1);
#pragma unroll
            for (int kb = 0; kb < 4; ++kb) mk[kb] = mkn[kb];
            if (kt < 30) {
                issue_kv((kt + 2) * 64);
                issue_mask(mkn, (kt + 2) * 64);
            }
        }
        __syncthreads();
    }

    // ---- epilogue: reduce lane-partial l, normalize, stage in LDS, store
    lp += __shfl_xor(lp, 16);
    lp += __shfl_xor(lp, 32);
    const float inv = 1.f / lp;
    float invr[4];
#pragma unroll
    for (int r = 0; r < 4; ++r) invr[r] = __shfl(inv, lg * 4 + r);
    u16* Ol = &Kl[0][0];            // Kl dead after loop (final barrier passed)
#pragma unroll
    for (int n = 0; n < 4; ++n)
#pragma unroll
        for (int r = 0; r < 4; ++r)
            Ol[(w * 16 + lg * 4 + r) * KS + n * 16 + lr16] = f2bf(Oa[n][r] * invr[r]);
    __syncthreads();
    {
        const int row = t >> 2, c0 = (t & 3) * 16;
        const u16* src = &Ol[row * KS + c0];
        u16* dstp = og + ((size_t)(b * SEQ + q0 + row)) * DM + h * HD + c0;
        *(float4*)dstp       = *(const float4*)src;
        *(float4*)(dstp + 8) = *(const float4*)(src + 8);
    }
}

// ---------------------------------------------------------------------------
extern "C" void kernel_launch(void* const* d_in, const int* in_sizes, int n_in,
                              void* d_out, int out_size, void* d_ws, size_t ws_size,
                              hipStream_t stream) {
    const float* x     = (const float*)d_in[0];
    const float* mask  = (const float*)d_in[1];
    const float* W_qkv = (const float*)d_in[2];
    const float* b_qkv = (const float*)d_in[3];
    const float* W_out = (const float*)d_in[4];
    const float* b_out = (const float*)d_in[5];
    float* out = (float*)d_out;

    const size_t NQ = (size_t)BATCH * NH * SEQ * HD;      // 4M elems
    u16* ws  = (u16*)d_ws;
    u16* xb  = ws;
    u16* wqb = xb + (size_t)4096 * 1024;
    u16* wob = wqb + (size_t)3072 * 1024;
    u16* qb  = wob + (size_t)1024 * 1024;
    u16* kb  = qb + NQ;
    u16* vb  = kb + NQ;
    u16* vtb = vb + NQ;
    u16* ob  = vtb + NQ;

    cast_all<<<(N4_X + N4_WQ + N4_WO) / 256, 256, 0, stream>>>(x, W_qkv, W_out, xb, wqb, wob);
    gemm_bf16<0><<<dim3(24, 32), 256, 0, stream>>>(xb, wqb, b_qkv, qb, kb, vb, nullptr);
    v_transpose<<<dim3(32, 32), 256, 0, stream>>>(vb, vtb);
    flash_attn<<<dim3(32 * NH * BATCH), 256, 0, stream>>>(qb, kb, vtb, mask, ob);
    gemm_bf16<1><<<dim3(8, 32), 256, 0, stream>>>(ob, wob, b_out, nullptr, nullptr, nullptr, out);
}

// Round 14
// 279.133 us; speedup vs baseline: 1.4831x; 1.4698x over previous
//
#include <hip/hip_runtime.h>
#include <hip/hip_bf16.h>

#define SEQ   2048
#define BATCH 2
#define NH    16
#define HD    64
#define DM    1024

typedef unsigned short u16;
typedef unsigned int   u32;
typedef __attribute__((ext_vector_type(8))) short bf8;   // 8 bf16 in 4 VGPRs
typedef __attribute__((ext_vector_type(4))) float f4;
typedef __attribute__((ext_vector_type(4))) u32  u32x4;

__device__ inline u16 f2bf(float f) {                    // round-to-nearest-even
    u32 u = __builtin_bit_cast(u32, f);
    return (u16)((u + 0x7FFFu + ((u >> 16) & 1u)) >> 16);
}

__device__ inline f4 MFMA(bf8 a, bf8 b, f4 c) {
    return __builtin_amdgcn_mfma_f32_16x16x32_bf16(a, b, c, 0, 0, 0);
}

// async global->LDS, 16B per lane (m97 lever). LDS dest must be lane-linear.
__device__ inline void gload16(const u16* g, u16* l) {
    __builtin_amdgcn_global_load_lds(
        (const __attribute__((address_space(1))) unsigned int*)(const void*)g,
        (__attribute__((address_space(3))) unsigned int*)(void*)l, 16, 0, 0);
}

// ---------------------------------------------------------------------------
// fused fp32 -> bf16 cast for x, W_qkv, W_out
// ---------------------------------------------------------------------------
#define N4_X  1048576
#define N4_WQ 786432
#define N4_WO 262144
__global__ __launch_bounds__(256) void cast_all(const float* __restrict__ x,
                                                const float* __restrict__ wq,
                                                const float* __restrict__ wo,
                                                u16* __restrict__ xb,
                                                u16* __restrict__ wqb,
                                                u16* __restrict__ wob) {
    const int i = blockIdx.x * 256 + threadIdx.x;
    const float* src;
    u16* dst;
    int j;
    if (i < N4_X)                { src = x;  dst = xb;  j = i; }
    else if (i < N4_X + N4_WQ)   { src = wq; dst = wqb; j = i - N4_X; }
    else                         { src = wo; dst = wob; j = i - N4_X - N4_WQ; }
    const float4 v = ((const float4*)src)[j];
    ushort4 o;
    o.x = f2bf(v.x); o.y = f2bf(v.y); o.z = f2bf(v.z); o.w = f2bf(v.w);
    ((ushort4*)dst)[j] = o;
}

// ---------------------------------------------------------------------------
// bf16 MFMA GEMM (m97 structure): 128x128 tile, 4 waves, 4x4 frags 16x16x32,
// BK=32, unpadded [128][32] LDS via global_load_lds dwordx4.
// MODE 0: qkv epilogue (scatter bf16 into q/k/v [B,H,S,hd]); MODE 1: fp32 out.
// ---------------------------------------------------------------------------
template<int MODE>
__global__ __launch_bounds__(256) void gemm_bf16(const u16* __restrict__ A,
                                                 const u16* __restrict__ Bm,
                                                 const float* __restrict__ bias,
                                                 u16* __restrict__ q_o,
                                                 u16* __restrict__ k_o,
                                                 u16* __restrict__ v_o,
                                                 float* __restrict__ f_o) {
    __shared__ __align__(16) u16 Al[128 * 32];
    __shared__ __align__(16) u16 Bl[128 * 32];
    const int t  = threadIdx.x;
    const int l  = t & 63, w = t >> 6;
    const int n0 = blockIdx.x * 128, m0 = blockIdx.y * 128;
    const int wr = w >> 1, wc = w & 1;
    const int lr16 = l & 15, lg = l >> 4;

    const f4 zf = {0.f, 0.f, 0.f, 0.f};
    f4 acc[4][4];
#pragma unroll
    for (int m = 0; m < 4; ++m)
#pragma unroll
        for (int n = 0; n < 4; ++n) acc[m][n] = zf;

    const int rw = t >> 2;
    const int kc = t & 3;

    for (int k0 = 0; k0 < DM; k0 += 32) {
        __syncthreads();
        gload16(&A[(size_t)(m0 + rw) * DM + k0 + kc * 8],       &Al[rw * 32 + kc * 8]);
        gload16(&A[(size_t)(m0 + 64 + rw) * DM + k0 + kc * 8],  &Al[(64 + rw) * 32 + kc * 8]);
        gload16(&Bm[(size_t)(n0 + rw) * DM + k0 + kc * 8],      &Bl[rw * 32 + kc * 8]);
        gload16(&Bm[(size_t)(n0 + 64 + rw) * DM + k0 + kc * 8], &Bl[(64 + rw) * 32 + kc * 8]);
        __syncthreads();
        bf8 af[4], bfr[4];
#pragma unroll
        for (int m = 0; m < 4; ++m)
            af[m] = *(const bf8*)&Al[(wr * 64 + m * 16 + lr16) * 32 + lg * 8];
#pragma unroll
        for (int n = 0; n < 4; ++n)
            bfr[n] = *(const bf8*)&Bl[(wc * 64 + n * 16 + lr16) * 32 + lg * 8];
        __builtin_amdgcn_s_setprio(1);
#pragma unroll
        for (int m = 0; m < 4; ++m)
#pragma unroll
            for (int n = 0; n < 4; ++n)
                acc[m][n] = MFMA(af[m], bfr[n], acc[m][n]);
        __builtin_amdgcn_s_setprio(0);
    }

#pragma unroll
    for (int m = 0; m < 4; ++m)
#pragma unroll
        for (int n = 0; n < 4; ++n)
#pragma unroll
            for (int r = 0; r < 4; ++r) {
                const int M = m0 + wr * 64 + m * 16 + lg * 4 + r;
                const int N = n0 + wc * 64 + n * 16 + lr16;
                const float val = acc[m][n][r] + bias[N];
                if (MODE == 0) {
                    const int b = M >> 11, s = M & (SEQ - 1);
                    const int h = N / 192, f = N % 192;
                    const int seg = f >> 6, c = f & 63;
                    u16* dst = (seg == 0) ? q_o : ((seg == 1) ? k_o : v_o);
                    dst[(((size_t)(b * NH + h)) * SEQ + s) * HD + c] = f2bf(val);
                } else {
                    f_o[(size_t)M * DM + N] = val;
                }
            }
}

// ---------------------------------------------------------------------------
// V transpose: v [BH][S][64] -> vt [BH][64][S]
// ---------------------------------------------------------------------------
__global__ __launch_bounds__(256) void v_transpose(const u16* __restrict__ v,
                                                   u16* __restrict__ vt) {
    __shared__ u16 tl[64][65];
    const int t  = threadIdx.x;
    const int s0 = blockIdx.x * 64;
    const int bh = blockIdx.y;
    const u16* src = v + ((size_t)bh * SEQ + s0) * HD;
#pragma unroll
    for (int i = 0; i < 2; ++i) {
        const int c = i * 256 + t, s = c >> 3, cc = c & 7;
        const float4 d = *(const float4*)&src[s * HD + cc * 8];
        const u16* dp = (const u16*)&d;
#pragma unroll
        for (int j = 0; j < 8; ++j) tl[s][cc * 8 + j] = dp[j];
    }
    __syncthreads();
    u16* dst = vt + (size_t)bh * HD * SEQ + s0;
#pragma unroll
    for (int i = 0; i < 2; ++i) {
        const int c = i * 256 + t, dim = c >> 3, sc = c & 7;
        __align__(16) u16 tmp[8];
#pragma unroll
        for (int j = 0; j < 8; ++j) tmp[j] = tl[sc * 8 + j][dim];
        *(float4*)&dst[(size_t)dim * SEQ + sc * 8] = *(const float4*)tmp;
    }
}

// ---------------------------------------------------------------------------
// MFMA flash attention v6: swapped QK^T (v5 math, verified) with
//  - K/V staged via global_load_lds into UNPADDED [64][64] LDS, bank conflicts
//    fixed by XOR-swizzling the per-lane GLOBAL source (granule g^(row&7));
//    reads apply the same involution. Zero staging VGPRs, zero ds_writes.
//  - 2-phase pipeline: {mask loads -> next-tile gloads -> compute -> barrier};
//    barrier's implicit vmcnt(0) drains staging. Masks issued BEFORE gloads so
//    their compiler wait is vmcnt(4), not a full drain.
//  - lane-local softmax (15 fmax + 2 shfl), lane-partial l, deferred max,
//    in-register P redistribution (16 bpermute + 8 select).
//  - LDS 32KB -> 4 blocks/CU; ~100 live VGPRs fits (256,4) cap 128, no spill.
// ---------------------------------------------------------------------------
__global__ __launch_bounds__(256, 4) void flash_attn(const u16* __restrict__ qg,
                                                     const u16* __restrict__ kg,
                                                     const u16* __restrict__ vtg,
                                                     const float* __restrict__ mask,
                                                     u16* __restrict__ og) {
    __shared__ __align__(16) u16 Kl[2 * 64 * 64];
    __shared__ __align__(16) u16 Vl[2 * 64 * 64];
    const int t = threadIdx.x, l = t & 63, w = t >> 6;
    const int lr16 = l & 15, lg = l >> 4;
    // chunked XCD map: XCD x owns 4 complete (b,h) K/V sets (2MB, L2-resident)
    const int bid = blockIdx.x;
    const int lb  = (bid & 7) * 128 + (bid >> 3);
    const int bh  = lb >> 5, qt = lb & 31;
    const int h = bh & 15, b = bh >> 4;
    const int q0 = qt * 64;
    const int qbase = q0 + w * 16;

    const float C1  = 0.18033688011f;   // 0.125 * log2(e)
    const float L2E = 1.44269504089f;

    // Q as B-operand frag: lane holds Q[q=qbase+lr16][d=lg*8+j]
    bf8 qf[2];
    {
        const u16* qp = qg + ((size_t)bh * SEQ + qbase + lr16) * HD + lg * 8;
        qf[0] = *(const bf8*)qp;
        qf[1] = *(const bf8*)(qp + 32);
    }

    const f4 zf = {0.f, 0.f, 0.f, 0.f};
    f4 Oa[4];                       // O[q=lg*4+r][dim=n*16+lr16]
#pragma unroll
    for (int n = 0; n < 4; ++n) Oa[n] = zf;
    float mr = -1e30f, lp = 0.f;    // per-lane softmax state for q = lr16

    const u16* Kb = kg  + (size_t)bh * SEQ * HD;
    const u16* Vb = vtg + (size_t)bh * HD * SEQ;

    // DMA-stage one 64-key tile: lane-linear LDS dest, XOR-swizzled global src.
    // phys granule c holds logical granule (c&7)^(row&7) of row c>>3.
    auto stage_kv = [&](int buf, int kv0) {
#pragma unroll
        for (int i = 0; i < 2; ++i) {
            const int c  = i * 256 + t;
            const int a  = c >> 3;                  // K key row / V dim row
            const int gl = (c & 7) ^ (a & 7);       // logical granule at this slot
            gload16(&Kb[(size_t)(kv0 + a) * HD + gl * 8], &Kl[buf * 4096 + c * 8]);
            gload16(&Vb[(size_t)a * SEQ + kv0 + gl * 8],  &Vl[buf * 4096 + c * 8]);
        }
    };

    stage_kv(0, 0);
    __syncthreads();                // implicit vmcnt(0): tile 0 landed

    for (int kt = 0; kt < 32; ++kt) {
        const int cur = kt & 1;
        const int kv0 = kt * 64;
        // ---- mask loads FIRST (their wait = vmcnt(#gloads), not 0)
        f4 mk[4];
        {
            const float* mrow = &mask[(size_t)(qbase + lr16) * SEQ + kv0 + lg * 4];
#pragma unroll
            for (int kb = 0; kb < 4; ++kb) mk[kb] = *(const f4*)(mrow + kb * 16);
        }
        // ---- issue next tile's DMA; lands during this tile's compute
        if (kt < 31) stage_kv(cur ^ 1, kv0 + 64);
        // ---- swapped QK^T: sc[kb] = S[key=kb*16+lg*4+r][q=lr16]
        f4 sc[4];
        __builtin_amdgcn_s_setprio(1);
#pragma unroll
        for (int kb = 0; kb < 4; ++kb) {
            const int krow = kb * 16 + lr16;
            const int p0 = lg ^ (krow & 7);
            const int p1 = (lg + 4) ^ (krow & 7);
            const bf8 k0 = *(const bf8*)&Kl[cur * 4096 + krow * 64 + p0 * 8];
            const bf8 k1 = *(const bf8*)&Kl[cur * 4096 + krow * 64 + p1 * 8];
            sc[kb] = MFMA(k1, qf[1], MFMA(k0, qf[0], zf));
        }
        __builtin_amdgcn_s_setprio(0);
#pragma unroll
        for (int kb = 0; kb < 4; ++kb)
#pragma unroll
            for (int r = 0; r < 4; ++r)
                sc[kb][r] = fmaf(sc[kb][r], C1, mk[kb][r] * L2E);
        // ---- row max: 15 local fmax + 2 shfl
        float rmax = fmaxf(
            fmaxf(fmaxf(fmaxf(sc[0][0], sc[0][1]), fmaxf(sc[0][2], sc[0][3])),
                  fmaxf(fmaxf(sc[1][0], sc[1][1]), fmaxf(sc[1][2], sc[1][3]))),
            fmaxf(fmaxf(fmaxf(sc[2][0], sc[2][1]), fmaxf(sc[2][2], sc[2][3])),
                  fmaxf(fmaxf(sc[3][0], sc[3][1]), fmaxf(sc[3][2], sc[3][3]))));
        rmax = fmaxf(rmax, __shfl_xor(rmax, 16));
        rmax = fmaxf(rmax, __shfl_xor(rmax, 32));
        // ---- deferred rescale (rare)
        if (__any(rmax > mr + 8.f)) {
            const float mn = fmaxf(mr, rmax);
            const float al = exp2f(mr - mn);
            mr = mn;
            lp *= al;
            float alr[4];
#pragma unroll
            for (int r = 0; r < 4; ++r) alr[r] = __shfl(al, lg * 4 + r);
#pragma unroll
            for (int n = 0; n < 4; ++n)
#pragma unroll
                for (int r = 0; r < 4; ++r) Oa[n][r] *= alr[r];
        }
        // ---- P = 2^(s-mr) (<=2^8), lane-partial l, pack bf16 pairs
        u32 pk[4][2];
#pragma unroll
        for (int kb = 0; kb < 4; ++kb) {
            const float p0 = exp2f(sc[kb][0] - mr);
            const float p1 = exp2f(sc[kb][1] - mr);
            const float p2 = exp2f(sc[kb][2] - mr);
            const float p3 = exp2f(sc[kb][3] - mr);
            lp += (p0 + p1) + (p2 + p3);
            pk[kb][0] = ((u32)f2bf(p1) << 16) | f2bf(p0);
            pk[kb][1] = ((u32)f2bf(p3) << 16) | f2bf(p2);
        }
        // ---- redistribute P -> PV A-frag (lane needs P[q=lr16][k=lg*8+j])
        const int s0 = (lg & 1) * 32 + lr16, s1 = s0 + 16;
        const bool hi = (lg & 2) != 0;
        u32x4 paw[2];
#pragma unroll
        for (int hf = 0; hf < 2; ++hf) {
            const int kbA = hf * 2, kbB = hf * 2 + 1;
            const u32 a0 = (u32)__shfl((int)pk[kbA][0], s0);
            const u32 a1 = (u32)__shfl((int)pk[kbA][1], s0);
            const u32 a2 = (u32)__shfl((int)pk[kbA][0], s1);
            const u32 a3 = (u32)__shfl((int)pk[kbA][1], s1);
            const u32 b0 = (u32)__shfl((int)pk[kbB][0], s0);
            const u32 b1 = (u32)__shfl((int)pk[kbB][1], s0);
            const u32 b2 = (u32)__shfl((int)pk[kbB][0], s1);
            const u32 b3 = (u32)__shfl((int)pk[kbB][1], s1);
            paw[hf][0] = hi ? b0 : a0;
            paw[hf][1] = hi ? b1 : a1;
            paw[hf][2] = hi ? b2 : a2;
            paw[hf][3] = hi ? b3 : a3;
        }
        const bf8 pa0 = __builtin_bit_cast(bf8, paw[0]);
        const bf8 pa1 = __builtin_bit_cast(bf8, paw[1]);
        // ---- PV: Oa[n] += P[q][k] * V[k][dim=n*16+lr16]
        __builtin_amdgcn_s_setprio(1);
#pragma unroll
        for (int n = 0; n < 4; ++n) {
            const int vrow = n * 16 + lr16;
            const int p0 = lg ^ (vrow & 7);
            const int p1 = (lg + 4) ^ (vrow & 7);
            const bf8 v0 = *(const bf8*)&Vl[cur * 4096 + vrow * 64 + p0 * 8];
            const bf8 v1 = *(const bf8*)&Vl[cur * 4096 + vrow * 64 + p1 * 8];
            Oa[n] = MFMA(pa1, v1, MFMA(pa0, v0, Oa[n]));
        }
        __builtin_amdgcn_s_setprio(0);
        // ---- barrier: drains vmcnt(0) -> next tile staged & everyone done
        __syncthreads();
    }

    // ---- epilogue: reduce lane-partial l, normalize, stage in LDS, store
    lp += __shfl_xor(lp, 16);
    lp += __shfl_xor(lp, 32);
    const float inv = 1.f / lp;
    float invr[4];
#pragma unroll
    for (int r = 0; r < 4; ++r) invr[r] = __shfl(inv, lg * 4 + r);
    u16* Ol = Kl;                   // Kl dead after final barrier; stride 68
#pragma unroll
    for (int n = 0; n < 4; ++n)
#pragma unroll
        for (int r = 0; r < 4; ++r)
            Ol[(w * 16 + lg * 4 + r) * 68 + n * 16 + lr16] = f2bf(Oa[n][r] * invr[r]);
    __syncthreads();
    {
        const int row = t >> 2, c0 = (t & 3) * 16;
        const u16* src = &Ol[row * 68 + c0];
        u16* dstp = og + ((size_t)(b * SEQ + q0 + row)) * DM + h * HD + c0;
        *(float4*)dstp       = *(const float4*)src;
        *(float4*)(dstp + 8) = *(const float4*)(src + 8);
    }
}

// ---------------------------------------------------------------------------
extern "C" void kernel_launch(void* const* d_in, const int* in_sizes, int n_in,
                              void* d_out, int out_size, void* d_ws, size_t ws_size,
                              hipStream_t stream) {
    const float* x     = (const float*)d_in[0];
    const float* mask  = (const float*)d_in[1];
    const float* W_qkv = (const float*)d_in[2];
    const float* b_qkv = (const float*)d_in[3];
    const float* W_out = (const float*)d_in[4];
    const float* b_out = (const float*)d_in[5];
    float* out = (float*)d_out;

    const size_t NQ = (size_t)BATCH * NH * SEQ * HD;      // 4M elems
    u16* ws  = (u16*)d_ws;
    u16* xb  = ws;
    u16* wqb = xb + (size_t)4096 * 1024;
    u16* wob = wqb + (size_t)3072 * 1024;
    u16* qb  = wob + (size_t)1024 * 1024;
    u16* kb  = qb + NQ;
    u16* vb  = kb + NQ;
    u16* vtb = vb + NQ;
    u16* ob  = vtb + NQ;

    cast_all<<<(N4_X + N4_WQ + N4_WO) / 256, 256, 0, stream>>>(x, W_qkv, W_out, xb, wqb, wob);
    gemm_bf16<0><<<dim3(24, 32), 256, 0, stream>>>(xb, wqb, b_qkv, qb, kb, vb, nullptr);
    v_transpose<<<dim3(32, 32), 256, 0, stream>>>(vb, vtb);
    flash_attn<<<dim3(32 * NH * BATCH), 256, 0, stream>>>(qb, kb, vtb, mask, ob);
    gemm_bf16<1><<<dim3(8, 32), 256, 0, stream>>>(ob, wob, b_out, nullptr, nullptr, nullptr, out);
}